// Round 1
// 578.303 us; speedup vs baseline: 1.1888x; 1.1888x over previous
//
#include <hip/hip_runtime.h>
#include <hip/hip_bf16.h>
#include <cstddef>

#define DIM 1024
#define NQ 16
#define NKV 4
#define HD 64
#define HID 2048
#define NE 8
#define SEQ 1024
#define EPSF 1e-6f
#define MAX_TILES 24   // max sum of ceil(cnt_e/64): 1024/64 + 8 = 24
#define GST 72         // LDS k-stride in bf16 elems: 144 B, 16B-aligned rows

typedef __hip_bfloat16 bf16;
typedef __attribute__((ext_vector_type(8))) short short8;   // 8 bf16 = one MFMA A/B frag
typedef __attribute__((ext_vector_type(4))) float floatx4;  // MFMA C/D frag

__device__ __forceinline__ unsigned int f2b(float f) {
    union { bf16 b; unsigned short s; } u;
    u.b = __float2bfloat16(f);
    return (unsigned int)u.s;
}
__device__ __forceinline__ unsigned int pk2(float a, float b) {
    return f2b(a) | (f2b(b) << 16);
}

// ---------------- RMSNorm (row of 1024, f32 in/out) ----------------
__global__ __launch_bounds__(256) void rmsnorm_kernel(const float* __restrict__ src,
                                                      const float* __restrict__ w,
                                                      float* __restrict__ dst)
{
    int row = blockIdx.x, tid = threadIdx.x;
    __shared__ float red[256];
    float vals[4];
    float sq = 0.f;
    size_t base = (size_t)row * DIM;
    #pragma unroll
    for (int i = 0; i < 4; i++) {
        int idx = tid + i * 256;
        float v = src[base + idx];
        vals[i] = v; sq += v * v;
    }
    red[tid] = sq; __syncthreads();
    for (int s = 128; s > 0; s >>= 1) {
        if (tid < s) red[tid] += red[tid + s];
        __syncthreads();
    }
    float rs = 1.0f / sqrtf(red[0] * (1.0f / DIM) + EPSF);
    #pragma unroll
    for (int i = 0; i < 4; i++) {
        int idx = tid + i * 256;
        dst[base + idx] = w[idx] * vals[i] * rs;
    }
}

// ---------------- MFMA bf16 tiled GEMM (64x64 tile, BK=64) ----------------
// C[M,N] = A[M,K](f32, bf16-converted in staging) @ B[K,N](f32 weights) + bias
// mode 0: C[row] = acc + bias
// mode 1: C[row] = acc + bias + resf[row]
// mode 2: tok=perm[row]; C[tok] = resf[tok] + acc + bias   (skip tok<0)
// Fragment layouts (gfx950 16x16x32 bf16):
//   A: m=lane&15, k=8*(lane>>4)+i   (guide-confirmed)
//   B: staged as B^T rows, same mapping with n=lane&15 (m92 gemm_bt pattern)
//   C/D: col=lane&15, row=4*(lane>>4)+reg   (m89/m91-verified)
__global__ __launch_bounds__(256) void gemm_kernel(
    const float* __restrict__ A, const float* __restrict__ B, const float* __restrict__ bias,
    float* __restrict__ C, const float* __restrict__ resf,
    const int* __restrict__ perm, const int* __restrict__ tile_expert,
    int N, int K, int mode)
{
    __shared__ short As[64 * GST];
    __shared__ short Bs[64 * GST];
    int tid = threadIdx.x;
    int mbase = blockIdx.y * 64, nbase = blockIdx.x * 64;

    size_t Beoff = 0, biasoff = 0;
    if (tile_expert) {
        int e = tile_expert[blockIdx.y];
        if (e < 0) return;
        Beoff = (size_t)e * K * N;
        biasoff = (size_t)e * N;
    }

    int ar = tid >> 4, ak = (tid & 15) << 2;        // A staging: 4 rows x float4
    int bn = tid & 63, bkk = (tid >> 6) << 4;       // B staging: col bn, 16 k-rows
    const float* BpBase = B + Beoff + (size_t)bkk * N + nbase + bn;

    int wv = tid >> 6, ln = tid & 63;
    int fm = (wv << 4) + (ln & 15);                 // a-frag row
    int fn = ln & 15;                               // b-frag col (within n-tile)
    int fk = (ln >> 4) << 3;                        // frag k offset

    floatx4 acc[4];
    #pragma unroll
    for (int nt = 0; nt < 4; nt++)
        #pragma unroll
        for (int r = 0; r < 4; r++) acc[nt][r] = 0.f;

    for (int kt = 0; kt < K; kt += 64) {
        __syncthreads();
        #pragma unroll
        for (int p = 0; p < 4; p++) {
            int m = (p << 4) + ar;
            float4 v = *(const float4*)(A + (size_t)(mbase + m) * K + kt + ak);
            uint2 wpk; wpk.x = pk2(v.x, v.y); wpk.y = pk2(v.z, v.w);
            *(uint2*)&As[m * GST + ak] = wpk;
        }
        {
            const float* bp = BpBase + (size_t)kt * N;
            unsigned int u[8];
            #pragma unroll
            for (int i = 0; i < 8; i++)
                u[i] = pk2(bp[(size_t)(2 * i) * N], bp[(size_t)(2 * i + 1) * N]);
            *(uint4*)&Bs[bn * GST + bkk]     = make_uint4(u[0], u[1], u[2], u[3]);
            *(uint4*)&Bs[bn * GST + bkk + 8] = make_uint4(u[4], u[5], u[6], u[7]);
        }
        __syncthreads();
        #pragma unroll
        for (int ks = 0; ks < 2; ks++) {
            short8 af = *(const short8*)&As[fm * GST + (ks << 5) + fk];
            #pragma unroll
            for (int nt = 0; nt < 4; nt++) {
                short8 bf = *(const short8*)&Bs[((nt << 4) + fn) * GST + (ks << 5) + fk];
                acc[nt] = __builtin_amdgcn_mfma_f32_16x16x32_bf16(af, bf, acc[nt], 0, 0, 0);
            }
        }
    }

    int rowb = mbase + (wv << 4) + ((ln >> 4) << 2);
    if (mode == 2) {
        int tk[4];
        #pragma unroll
        for (int r = 0; r < 4; r++) tk[r] = perm[rowb + r];
        #pragma unroll
        for (int nt = 0; nt < 4; nt++) {
            int col = nbase + (nt << 4) + fn;
            float bsv = bias[biasoff + col];
            #pragma unroll
            for (int r = 0; r < 4; r++)
                if (tk[r] >= 0)
                    C[(size_t)tk[r] * N + col] = resf[(size_t)tk[r] * N + col] + acc[nt][r] + bsv;
        }
    } else {
        #pragma unroll
        for (int nt = 0; nt < 4; nt++) {
            int col = nbase + (nt << 4) + fn;
            float bsv = bias[col];
            #pragma unroll
            for (int r = 0; r < 4; r++) {
                float vv = acc[nt][r] + bsv;
                if (mode == 1) vv += resf[(size_t)(rowb + r) * N + col];
                C[(size_t)(rowb + r) * N + col] = vv;
            }
        }
    }
}

// ---------------- Fused MoE up-proj + SwiGLU (MFMA bf16, dual-B) ----------------
__global__ __launch_bounds__(256) void moe1_kernel(
    const float* __restrict__ A,        // h2 [SEQ][DIM]
    const float* __restrict__ W1,       // [E][DIM][2*HID]
    const float* __restrict__ b1,       // [E][2*HID]
    float* __restrict__ act,            // [MAX_TILES*64][HID]
    const int* __restrict__ perm,
    const int* __restrict__ tile_expert)
{
    __shared__ short As[64 * GST];
    __shared__ short B1s[64 * GST];
    __shared__ short B2s[64 * GST];
    int tid = threadIdx.x;
    int mbase = blockIdx.y * 64, nbase = blockIdx.x * 64;
    int e = tile_expert[blockIdx.y];
    if (e < 0) return;
    const float* Wp = W1 + (size_t)e * DIM * (2 * HID);
    const float* bp1 = b1 + (size_t)e * (2 * HID);

    int ar = tid >> 4, ak = (tid & 15) << 2;
    int tok[4];
    #pragma unroll
    for (int p = 0; p < 4; p++) tok[p] = perm[mbase + (p << 4) + ar];

    int bn = tid & 63, bkk = (tid >> 6) << 4;
    const float* BpBase = Wp + (size_t)bkk * (2 * HID) + nbase + bn;

    int wv = tid >> 6, ln = tid & 63;
    int fm = (wv << 4) + (ln & 15);
    int fn = ln & 15;
    int fk = (ln >> 4) << 3;

    floatx4 acc1[4], acc2[4];
    #pragma unroll
    for (int nt = 0; nt < 4; nt++)
        #pragma unroll
        for (int r = 0; r < 4; r++) { acc1[nt][r] = 0.f; acc2[nt][r] = 0.f; }

    for (int kt = 0; kt < DIM; kt += 64) {
        __syncthreads();
        #pragma unroll
        for (int p = 0; p < 4; p++) {
            int m = (p << 4) + ar;
            float4 v = (tok[p] >= 0)
                ? *(const float4*)(A + (size_t)tok[p] * DIM + kt + ak)
                : make_float4(0.f, 0.f, 0.f, 0.f);
            uint2 wpk; wpk.x = pk2(v.x, v.y); wpk.y = pk2(v.z, v.w);
            *(uint2*)&As[m * GST + ak] = wpk;
        }
        {
            const float* bp = BpBase + (size_t)kt * (2 * HID);
            unsigned int u1[8], u2[8];
            #pragma unroll
            for (int i = 0; i < 8; i++) {
                u1[i] = pk2(bp[(size_t)(2 * i) * (2 * HID)],
                            bp[(size_t)(2 * i + 1) * (2 * HID)]);
                u2[i] = pk2(bp[(size_t)(2 * i) * (2 * HID) + HID],
                            bp[(size_t)(2 * i + 1) * (2 * HID) + HID]);
            }
            *(uint4*)&B1s[bn * GST + bkk]     = make_uint4(u1[0], u1[1], u1[2], u1[3]);
            *(uint4*)&B1s[bn * GST + bkk + 8] = make_uint4(u1[4], u1[5], u1[6], u1[7]);
            *(uint4*)&B2s[bn * GST + bkk]     = make_uint4(u2[0], u2[1], u2[2], u2[3]);
            *(uint4*)&B2s[bn * GST + bkk + 8] = make_uint4(u2[4], u2[5], u2[6], u2[7]);
        }
        __syncthreads();
        #pragma unroll
        for (int ks = 0; ks < 2; ks++) {
            short8 af = *(const short8*)&As[fm * GST + (ks << 5) + fk];
            #pragma unroll
            for (int nt = 0; nt < 4; nt++) {
                int bo = ((nt << 4) + fn) * GST + (ks << 5) + fk;
                short8 bf1 = *(const short8*)&B1s[bo];
                short8 bf2 = *(const short8*)&B2s[bo];
                acc1[nt] = __builtin_amdgcn_mfma_f32_16x16x32_bf16(af, bf1, acc1[nt], 0, 0, 0);
                acc2[nt] = __builtin_amdgcn_mfma_f32_16x16x32_bf16(af, bf2, acc2[nt], 0, 0, 0);
            }
        }
    }

    int rowb = mbase + (wv << 4) + ((ln >> 4) << 2);
    #pragma unroll
    for (int nt = 0; nt < 4; nt++) {
        int col = nbase + (nt << 4) + fn;
        float bs1 = bp1[col];
        float bs2 = bp1[HID + col];
        #pragma unroll
        for (int r = 0; r < 4; r++) {
            float u1 = acc1[nt][r] + bs1;
            float u2 = acc2[nt][r] + bs2;
            act[(size_t)(rowb + r) * HID + col] = u1 * (1.0f / (1.0f + expf(-u2)));
        }
    }
}

// ---------------- RoPE + per-head RMSNorm (one wave per (t, head)) ----------------
__global__ __launch_bounds__(64) void rope_rms_kernel(float* __restrict__ x,
                                                      const float* __restrict__ w, int nh)
{
    int t = blockIdx.x, h = blockIdx.y, d = threadIdx.x;
    int base = (t * nh + h) * HD;
    int i = d & 31;
    float x1 = x[base + i];
    float x2 = x[base + 32 + i];
    float inv = 1.0f / powf(10000.0f, (float)(2 * i) * (1.0f / HD));
    float fr = (float)t * inv;
    float c = cosf(fr), s = sinf(fr);
    float r = (d < 32) ? (x1 * c - x2 * s) : (x1 * s + x2 * c);
    float sq = r * r;
    #pragma unroll
    for (int m = 32; m >= 1; m >>= 1) sq += __shfl_xor(sq, m);
    float rs = 1.0f / sqrtf(sq * (1.0f / HD) + EPSF);
    __syncthreads();
    x[base + d] = r * rs * w[d];
}

// ---------------- Flash-style causal GQA attention ----------------
__global__ __launch_bounds__(256) void fattn_kernel(const float* __restrict__ q,
                                                    const float* __restrict__ k,
                                                    const float* __restrict__ v,
                                                    float* __restrict__ o)
{
    __shared__ float QsT[64][64];
    __shared__ float KsT[64][64];
    __shared__ float Vs[64][64];
    __shared__ float Ps[64][64];

    int h = blockIdx.x;
    int qt = blockIdx.y;
    int kvh = h >> 2;
    int tid = threadIdx.x;
    int tx = tid & 15, ty = tid >> 4;
    int lr = tid >> 4;
    int lc = (tid & 15) << 2;
    int qbase = qt * 64;

    #pragma unroll
    for (int rr = 0; rr < 64; rr += 16) {
        int r = rr + lr;
        float4 av = *(const float4*)(q + ((size_t)(qbase + r) * NQ + h) * HD + lc);
        QsT[lc + 0][r] = av.x; QsT[lc + 1][r] = av.y;
        QsT[lc + 2][r] = av.z; QsT[lc + 3][r] = av.w;
    }

    float O[4][4];
    float m_i[4], l_i[4];
    #pragma unroll
    for (int i = 0; i < 4; i++) {
        m_i[i] = -INFINITY; l_i[i] = 0.f;
        #pragma unroll
        for (int j = 0; j < 4; j++) O[i][j] = 0.f;
    }

    for (int kt = 0; kt <= qt; kt++) {
        int kbase = kt * 64;
        __syncthreads();
        #pragma unroll
        for (int rr = 0; rr < 64; rr += 16) {
            int r = rr + lr;
            size_t rowoff = ((size_t)(kbase + r) * NKV + kvh) * HD + lc;
            float4 kv4 = *(const float4*)(k + rowoff);
            KsT[lc + 0][r] = kv4.x; KsT[lc + 1][r] = kv4.y;
            KsT[lc + 2][r] = kv4.z; KsT[lc + 3][r] = kv4.w;
            float4 vv4 = *(const float4*)(v + rowoff);
            *(float4*)&Vs[r][lc] = vv4;
        }
        __syncthreads();

        float S[4][4];
        #pragma unroll
        for (int i = 0; i < 4; i++)
            #pragma unroll
            for (int j = 0; j < 4; j++) S[i][j] = 0.f;
        for (int d = 0; d < 64; d++) {
            float4 a = *(const float4*)&QsT[d][ty << 2];
            float4 b = *(const float4*)&KsT[d][tx << 2];
            float ar[4] = {a.x, a.y, a.z, a.w};
            float br[4] = {b.x, b.y, b.z, b.w};
            #pragma unroll
            for (int i = 0; i < 4; i++)
                #pragma unroll
                for (int j = 0; j < 4; j++) S[i][j] += ar[i] * br[j];
        }
        #pragma unroll
        for (int i = 0; i < 4; i++)
            #pragma unroll
            for (int j = 0; j < 4; j++) S[i][j] *= 0.125f;

        if (kt == qt) {
            #pragma unroll
            for (int i = 0; i < 4; i++)
                #pragma unroll
                for (int j = 0; j < 4; j++)
                    if ((tx << 2) + j > (ty << 2) + i) S[i][j] = -1e30f;
        }

        float tm[4];
        #pragma unroll
        for (int i = 0; i < 4; i++)
            tm[i] = fmaxf(fmaxf(S[i][0], S[i][1]), fmaxf(S[i][2], S[i][3]));
        #pragma unroll
        for (int mk = 1; mk < 16; mk <<= 1)
            #pragma unroll
            for (int i = 0; i < 4; i++) tm[i] = fmaxf(tm[i], __shfl_xor(tm[i], mk));

        float alpha[4], ts[4];
        #pragma unroll
        for (int i = 0; i < 4; i++) {
            float mn = fmaxf(m_i[i], tm[i]);
            alpha[i] = expf(m_i[i] - mn);
            m_i[i] = mn;
            float s = 0.f;
            #pragma unroll
            for (int j = 0; j < 4; j++) {
                float p = expf(S[i][j] - mn);
                S[i][j] = p; s += p;
            }
            ts[i] = s;
        }
        #pragma unroll
        for (int mk = 1; mk < 16; mk <<= 1)
            #pragma unroll
            for (int i = 0; i < 4; i++) ts[i] += __shfl_xor(ts[i], mk);
        #pragma unroll
        for (int i = 0; i < 4; i++) {
            l_i[i] = alpha[i] * l_i[i] + ts[i];
            #pragma unroll
            for (int j = 0; j < 4; j++) O[i][j] *= alpha[i];
        }

        #pragma unroll
        for (int i = 0; i < 4; i++)
            #pragma unroll
            for (int j = 0; j < 4; j++)
                Ps[(tx << 2) + j][(ty << 2) + i] = S[i][j];
        __syncthreads();
        for (int s = 0; s < 64; s++) {
            float4 a = *(const float4*)&Ps[s][ty << 2];
            float4 b = *(const float4*)&Vs[s][tx << 2];
            float ar[4] = {a.x, a.y, a.z, a.w};
            float br[4] = {b.x, b.y, b.z, b.w};
            #pragma unroll
            for (int i = 0; i < 4; i++)
                #pragma unroll
                for (int j = 0; j < 4; j++) O[i][j] += ar[i] * br[j];
        }
    }

    #pragma unroll
    for (int i = 0; i < 4; i++) {
        float invl = 1.0f / l_i[i];
        int t = qbase + (ty << 2) + i;
        #pragma unroll
        for (int j = 0; j < 4; j++)
            o[((size_t)t * NQ + h) * HD + (tx << 2) + j] = O[i][j] * invl;
    }
}

// ---------------- Per-head sigmoid gate (in-place) ----------------
__global__ __launch_bounds__(64) void gate_kernel(float* __restrict__ o,
                                                  const float* __restrict__ Wg,
                                                  const float* __restrict__ bg)
{
    int t = blockIdx.x, h = blockIdx.y, d = threadIdx.x;
    __shared__ float ao[HD];
    int base = (t * NQ + h) * HD;
    ao[d] = o[base + d];
    __syncthreads();
    float acc = bg[d];
    #pragma unroll 8
    for (int e = 0; e < HD; e++) acc += ao[e] * Wg[e * HD + d];
    float g = 1.0f / (1.0f + expf(-acc));
    o[base + d] = ao[d] * g;
}

// ---------------- Router: logits + argmax (one wave per token) ----------------
__global__ __launch_bounds__(64) void router_kernel(const float* __restrict__ h2,
                                                    const float* __restrict__ Wr,
                                                    const float* __restrict__ br,
                                                    int* __restrict__ top1)
{
    int t = blockIdx.x, lane = threadIdx.x;
    float acc[NE] = {0.f, 0.f, 0.f, 0.f, 0.f, 0.f, 0.f, 0.f};
    for (int d = lane; d < DIM; d += 64) {
        float hv = h2[(size_t)t * DIM + d];
        float4 w0 = *(const float4*)(Wr + (size_t)d * NE);
        float4 w1 = *(const float4*)(Wr + (size_t)d * NE + 4);
        acc[0] += hv * w0.x; acc[1] += hv * w0.y;
        acc[2] += hv * w0.z; acc[3] += hv * w0.w;
        acc[4] += hv * w1.x; acc[5] += hv * w1.y;
        acc[6] += hv * w1.z; acc[7] += hv * w1.w;
    }
    #pragma unroll
    for (int e = 0; e < NE; e++)
        for (int off = 32; off >= 1; off >>= 1) acc[e] += __shfl_down(acc[e], off);
    if (lane == 0) {
        float best = acc[0] + br[0]; int be = 0;
        #pragma unroll
        for (int e = 1; e < NE; e++) {
            float l = acc[e] + br[e];
            if (l > best) { best = l; be = e; }   // strict > : first max wins (np.argmax)
        }
        top1[t] = be;
    }
}

// ---------------- Bucket tokens by expert into 64-padded tiles ----------------
// Single-wave parallel version. Old kernel was tid==0 serial over 2x1024
// dependent LDS iterations (~122 us, top dispatch in rocprof, all pipes idle).
// Here: each lane owns 16 contiguous tokens; per-lane histogram (expert loop
// statically unrolled -> register-indexed, no scratch); cross-lane exclusive
// prefix per expert via 6 shfl_up steps; stable per-expert scatter.
__global__ __launch_bounds__(64) void bucket_kernel(const int* __restrict__ top1,
                                                    int* __restrict__ perm,
                                                    int* __restrict__ tile_expert)
{
    int lane = threadIdx.x;

    // load 16 tokens' experts (4 x int4, coalesced: wave covers 4KB/instr)
    int e_of[16];
    {
        const int4* tp = (const int4*)(top1 + lane * 16);
        #pragma unroll
        for (int c = 0; c < 4; c++) {
            int4 v = tp[c];
            e_of[c * 4 + 0] = v.x & 7;
            e_of[c * 4 + 1] = v.y & 7;
            e_of[c * 4 + 2] = v.z & 7;
            e_of[c * 4 + 3] = v.w & 7;
        }
    }

    // per-lane histogram, static expert indexing only
    int cnt[NE];
    #pragma unroll
    for (int e = 0; e < NE; e++) {
        int c = 0;
        #pragma unroll
        for (int i = 0; i < 16; i++) c += (e_of[i] == e) ? 1 : 0;
        cnt[e] = c;
    }

    // inclusive scan across lanes per expert (6 shfl_up steps)
    int pre[NE];
    #pragma unroll
    for (int e = 0; e < NE; e++) pre[e] = cnt[e];
    #pragma unroll
    for (int off = 1; off < 64; off <<= 1) {
        #pragma unroll
        for (int e = 0; e < NE; e++) {
            int t = __shfl_up(pre[e], off);
            if (lane >= off) pre[e] += t;
        }
    }
    // totals (lane 63 holds inclusive total), then make exclusive
    int tot[NE];
    #pragma unroll
    for (int e = 0; e < NE; e++) {
        tot[e] = __shfl(pre[e], 63);
        pre[e] -= cnt[e];
    }

    // 64-padded tile offsets (uniform across lanes)
    int off_e[NE + 1];
    off_e[0] = 0;
    #pragma unroll
    for (int e = 0; e < NE; e++)
        off_e[e + 1] = off_e[e] + (((tot[e] + 63) >> 6) << 6);

    // tile -> expert (slots beyond off_e[NE] stay -1; empty experts never match)
    if (lane < MAX_TILES) {
        int tb = lane << 6;
        int te = -1;
        #pragma unroll
        for (int e = 0; e < NE; e++)
            if (tb >= off_e[e] && tb < off_e[e + 1]) te = e;
        tile_expert[lane] = te;
    }

    // -1 padding only in the used tiles' tails (unused tiles have texp=-1)
    #pragma unroll
    for (int e = 0; e < NE; e++)
        for (int i = off_e[e] + tot[e] + lane; i < off_e[e + 1]; i += 64)
            perm[i] = -1;

    // stable scatter: per-expert unrolled inner loop, predicated stores,
    // position register advances only on match (no runtime-indexed arrays)
    #pragma unroll
    for (int e = 0; e < NE; e++) {
        int pos = off_e[e] + pre[e];
        #pragma unroll
        for (int i = 0; i < 16; i++) {
            if (e_of[i] == e) { perm[pos] = lane * 16 + i; pos++; }
        }
    }
}

extern "C" void kernel_launch(void* const* d_in, const int* in_sizes, int n_in,
                              void* d_out, int out_size, void* d_ws, size_t ws_size,
                              hipStream_t stream)
{
    const float* x    = (const float*)d_in[0];
    const float* ln1w = (const float*)d_in[1];
    const float* ln2w = (const float*)d_in[2];
    const float* Wq   = (const float*)d_in[3];
    const float* bq   = (const float*)d_in[4];
    const float* Wk   = (const float*)d_in[5];
    const float* bk   = (const float*)d_in[6];
    const float* Wv   = (const float*)d_in[7];
    const float* bv   = (const float*)d_in[8];
    const float* qnw  = (const float*)d_in[9];
    const float* knw  = (const float*)d_in[10];
    const float* Wg   = (const float*)d_in[11];
    const float* bg   = (const float*)d_in[12];
    const float* Wo   = (const float*)d_in[13];
    const float* bo   = (const float*)d_in[14];
    const float* Wr   = (const float*)d_in[15];
    const float* br   = (const float*)d_in[16];
    const float* W1   = (const float*)d_in[17];
    const float* b1   = (const float*)d_in[18];
    const float* W2   = (const float*)d_in[19];
    const float* b2   = (const float*)d_in[20];
    float* out = (float*)d_out;
    (void)in_sizes; (void)n_in; (void)out_size; (void)ws_size;

    char* ws = (char*)d_ws;
    float* h    = (float*)(ws);
    float* q    = (float*)(ws + ((size_t)4  << 20));
    float* kbuf = (float*)(ws + ((size_t)8  << 20));
    float* vbuf = (float*)(ws + ((size_t)9  << 20));
    float* ao   = (float*)(ws + ((size_t)10 << 20));
    float* x2   = (float*)(ws);                          // over h (dead)
    float* h2   = (float*)(ws + ((size_t)4  << 20));     // over q (dead)
    float* act  = (float*)(ws + ((size_t)8  << 20));     // over k/v/ao (dead), 12 MB
    int* top1   = (int*)  (ws + ((size_t)20 << 20));
    int* perm   = top1 + 2048;
    int* texp   = perm + MAX_TILES * 64;

    rmsnorm_kernel<<<SEQ, 256, 0, stream>>>(x, ln1w, h);
    gemm_kernel<<<dim3(DIM / 64, SEQ / 64), 256, 0, stream>>>(
        h, Wq, bq, q, nullptr, nullptr, nullptr, DIM, DIM, 0);
    gemm_kernel<<<dim3((NKV * HD) / 64, SEQ / 64), 256, 0, stream>>>(
        h, Wk, bk, kbuf, nullptr, nullptr, nullptr, NKV * HD, DIM, 0);
    gemm_kernel<<<dim3((NKV * HD) / 64, SEQ / 64), 256, 0, stream>>>(
        h, Wv, bv, vbuf, nullptr, nullptr, nullptr, NKV * HD, DIM, 0);
    rope_rms_kernel<<<dim3(SEQ, NQ),  64, 0, stream>>>(q,    qnw, NQ);
    rope_rms_kernel<<<dim3(SEQ, NKV), 64, 0, stream>>>(kbuf, knw, NKV);
    fattn_kernel<<<dim3(NQ, SEQ / 64), 256, 0, stream>>>(q, kbuf, vbuf, ao);
    gate_kernel<<<dim3(SEQ, NQ), 64, 0, stream>>>(ao, Wg, bg);
    gemm_kernel<<<dim3(DIM / 64, SEQ / 64), 256, 0, stream>>>(
        ao, Wo, bo, x2, x, nullptr, nullptr, DIM, DIM, 1);
    rmsnorm_kernel<<<SEQ, 256, 0, stream>>>(x2, ln2w, h2);
    router_kernel<<<SEQ, 64, 0, stream>>>(h2, Wr, br, top1);
    bucket_kernel<<<1, 64, 0, stream>>>(top1, perm, texp);
    moe1_kernel<<<dim3(HID / 64, MAX_TILES), 256, 0, stream>>>(
        h2, W1, b1, act, perm, texp);
    gemm_kernel<<<dim3(DIM / 64, MAX_TILES), 256, 0, stream>>>(
        act, W2, b2, out, x2, perm, texp, DIM, HID, 2);
}

// Round 2
// 495.716 us; speedup vs baseline: 1.3868x; 1.1666x over previous
//
#include <hip/hip_runtime.h>
#include <hip/hip_bf16.h>
#include <cstddef>

#define DIM 1024
#define NQ 16
#define NKV 4
#define HD 64
#define HID 2048
#define NE 8
#define SEQ 1024
#define EPSF 1e-6f
#define MAX_TILES 24   // max sum of ceil(cnt_e/64): 1024/64 + 8 = 24
#define GST 72         // LDS k-stride in bf16 elems: 144 B, 16B-aligned rows

typedef __hip_bfloat16 bf16;
typedef __attribute__((ext_vector_type(8))) short short8;   // 8 bf16 = one MFMA A/B frag
typedef __attribute__((ext_vector_type(4))) float floatx4;  // MFMA C/D frag

typedef union { short8 s; unsigned int u[4]; } s8u;

__device__ __forceinline__ unsigned int f2b(float f) {
    union { bf16 b; unsigned short s; } u;
    u.b = __float2bfloat16(f);
    return (unsigned int)u.s;
}
__device__ __forceinline__ unsigned int pk2(float a, float b) {
    return f2b(a) | (f2b(b) << 16);
}

// ---------------- RMSNorm (row of 1024, f32 in/out) ----------------
__global__ __launch_bounds__(256) void rmsnorm_kernel(const float* __restrict__ src,
                                                      const float* __restrict__ w,
                                                      float* __restrict__ dst)
{
    int row = blockIdx.x, tid = threadIdx.x;
    __shared__ float red[256];
    float vals[4];
    float sq = 0.f;
    size_t base = (size_t)row * DIM;
    #pragma unroll
    for (int i = 0; i < 4; i++) {
        int idx = tid + i * 256;
        float v = src[base + idx];
        vals[i] = v; sq += v * v;
    }
    red[tid] = sq; __syncthreads();
    for (int s = 128; s > 0; s >>= 1) {
        if (tid < s) red[tid] += red[tid + s];
        __syncthreads();
    }
    float rs = 1.0f / sqrtf(red[0] * (1.0f / DIM) + EPSF);
    #pragma unroll
    for (int i = 0; i < 4; i++) {
        int idx = tid + i * 256;
        dst[base + idx] = w[idx] * vals[i] * rs;
    }
}

// ---------------- MFMA bf16 tiled GEMM (64x64 tile, BK=64) ----------------
// Fragment layouts (gfx950 16x16x32 bf16):
//   A: m=lane&15, k=8*(lane>>4)+i
//   B: staged as B^T rows (Bs[n][k]), n=lane&15, k=8*(lane>>4)+i
//   C/D: col=lane&15, row=4*(lane>>4)+reg   (m89/m91-verified)
__global__ __launch_bounds__(256) void gemm_kernel(
    const float* __restrict__ A, const float* __restrict__ B, const float* __restrict__ bias,
    float* __restrict__ C, const float* __restrict__ resf,
    const int* __restrict__ perm, const int* __restrict__ tile_expert,
    int N, int K, int mode)
{
    __shared__ short As[64 * GST];
    __shared__ short Bs[64 * GST];
    int tid = threadIdx.x;
    int mbase = blockIdx.y * 64, nbase = blockIdx.x * 64;

    size_t Beoff = 0, biasoff = 0;
    if (tile_expert) {
        int e = tile_expert[blockIdx.y];
        if (e < 0) return;
        Beoff = (size_t)e * K * N;
        biasoff = (size_t)e * N;
    }

    int ar = tid >> 4, ak = (tid & 15) << 2;        // A staging: 4 rows x float4
    int bn = tid & 63, bkk = (tid >> 6) << 4;       // B staging: col bn, 16 k-rows
    const float* BpBase = B + Beoff + (size_t)bkk * N + nbase + bn;

    int wv = tid >> 6, ln = tid & 63;
    int fm = (wv << 4) + (ln & 15);                 // a-frag row
    int fn = ln & 15;                               // b-frag col (within n-tile)
    int fk = (ln >> 4) << 3;                        // frag k offset

    floatx4 acc[4];
    #pragma unroll
    for (int nt = 0; nt < 4; nt++)
        #pragma unroll
        for (int r = 0; r < 4; r++) acc[nt][r] = 0.f;

    for (int kt = 0; kt < K; kt += 64) {
        __syncthreads();
        #pragma unroll
        for (int p = 0; p < 4; p++) {
            int m = (p << 4) + ar;
            float4 v = *(const float4*)(A + (size_t)(mbase + m) * K + kt + ak);
            uint2 wpk; wpk.x = pk2(v.x, v.y); wpk.y = pk2(v.z, v.w);
            *(uint2*)&As[m * GST + ak] = wpk;
        }
        {
            const float* bp = BpBase + (size_t)kt * N;
            unsigned int u[8];
            #pragma unroll
            for (int i = 0; i < 8; i++)
                u[i] = pk2(bp[(size_t)(2 * i) * N], bp[(size_t)(2 * i + 1) * N]);
            *(uint4*)&Bs[bn * GST + bkk]     = make_uint4(u[0], u[1], u[2], u[3]);
            *(uint4*)&Bs[bn * GST + bkk + 8] = make_uint4(u[4], u[5], u[6], u[7]);
        }
        __syncthreads();
        #pragma unroll
        for (int ks = 0; ks < 2; ks++) {
            short8 af = *(const short8*)&As[fm * GST + (ks << 5) + fk];
            #pragma unroll
            for (int nt = 0; nt < 4; nt++) {
                short8 bf = *(const short8*)&Bs[((nt << 4) + fn) * GST + (ks << 5) + fk];
                acc[nt] = __builtin_amdgcn_mfma_f32_16x16x32_bf16(af, bf, acc[nt], 0, 0, 0);
            }
        }
    }

    int rowb = mbase + (wv << 4) + ((ln >> 4) << 2);
    if (mode == 2) {
        int tk[4];
        #pragma unroll
        for (int r = 0; r < 4; r++) tk[r] = perm[rowb + r];
        #pragma unroll
        for (int nt = 0; nt < 4; nt++) {
            int col = nbase + (nt << 4) + fn;
            float bsv = bias[biasoff + col];
            #pragma unroll
            for (int r = 0; r < 4; r++)
                if (tk[r] >= 0)
                    C[(size_t)tk[r] * N + col] = resf[(size_t)tk[r] * N + col] + acc[nt][r] + bsv;
        }
    } else {
        #pragma unroll
        for (int nt = 0; nt < 4; nt++) {
            int col = nbase + (nt << 4) + fn;
            float bsv = bias[col];
            #pragma unroll
            for (int r = 0; r < 4; r++) {
                float vv = acc[nt][r] + bsv;
                if (mode == 1) vv += resf[(size_t)(rowb + r) * N + col];
                C[(size_t)(rowb + r) * N + col] = vv;
            }
        }
    }
}

// ---------------- Fused MoE up-proj + SwiGLU (MFMA bf16, dual-B) ----------------
__global__ __launch_bounds__(256) void moe1_kernel(
    const float* __restrict__ A,        // h2 [SEQ][DIM]
    const float* __restrict__ W1,       // [E][DIM][2*HID]
    const float* __restrict__ b1,       // [E][2*HID]
    float* __restrict__ act,            // [MAX_TILES*64][HID]
    const int* __restrict__ perm,
    const int* __restrict__ tile_expert)
{
    __shared__ short As[64 * GST];
    __shared__ short B1s[64 * GST];
    __shared__ short B2s[64 * GST];
    int tid = threadIdx.x;
    int mbase = blockIdx.y * 64, nbase = blockIdx.x * 64;
    int e = tile_expert[blockIdx.y];
    if (e < 0) return;
    const float* Wp = W1 + (size_t)e * DIM * (2 * HID);
    const float* bp1 = b1 + (size_t)e * (2 * HID);

    int ar = tid >> 4, ak = (tid & 15) << 2;
    int tok[4];
    #pragma unroll
    for (int p = 0; p < 4; p++) tok[p] = perm[mbase + (p << 4) + ar];

    int bn = tid & 63, bkk = (tid >> 6) << 4;
    const float* BpBase = Wp + (size_t)bkk * (2 * HID) + nbase + bn;

    int wv = tid >> 6, ln = tid & 63;
    int fm = (wv << 4) + (ln & 15);
    int fn = ln & 15;
    int fk = (ln >> 4) << 3;

    floatx4 acc1[4], acc2[4];
    #pragma unroll
    for (int nt = 0; nt < 4; nt++)
        #pragma unroll
        for (int r = 0; r < 4; r++) { acc1[nt][r] = 0.f; acc2[nt][r] = 0.f; }

    for (int kt = 0; kt < DIM; kt += 64) {
        __syncthreads();
        #pragma unroll
        for (int p = 0; p < 4; p++) {
            int m = (p << 4) + ar;
            float4 v = (tok[p] >= 0)
                ? *(const float4*)(A + (size_t)tok[p] * DIM + kt + ak)
                : make_float4(0.f, 0.f, 0.f, 0.f);
            uint2 wpk; wpk.x = pk2(v.x, v.y); wpk.y = pk2(v.z, v.w);
            *(uint2*)&As[m * GST + ak] = wpk;
        }
        {
            const float* bp = BpBase + (size_t)kt * (2 * HID);
            unsigned int u1[8], u2[8];
            #pragma unroll
            for (int i = 0; i < 8; i++) {
                u1[i] = pk2(bp[(size_t)(2 * i) * (2 * HID)],
                            bp[(size_t)(2 * i + 1) * (2 * HID)]);
                u2[i] = pk2(bp[(size_t)(2 * i) * (2 * HID) + HID],
                            bp[(size_t)(2 * i + 1) * (2 * HID) + HID]);
            }
            *(uint4*)&B1s[bn * GST + bkk]     = make_uint4(u1[0], u1[1], u1[2], u1[3]);
            *(uint4*)&B1s[bn * GST + bkk + 8] = make_uint4(u1[4], u1[5], u1[6], u1[7]);
            *(uint4*)&B2s[bn * GST + bkk]     = make_uint4(u2[0], u2[1], u2[2], u2[3]);
            *(uint4*)&B2s[bn * GST + bkk + 8] = make_uint4(u2[4], u2[5], u2[6], u2[7]);
        }
        __syncthreads();
        #pragma unroll
        for (int ks = 0; ks < 2; ks++) {
            short8 af = *(const short8*)&As[fm * GST + (ks << 5) + fk];
            #pragma unroll
            for (int nt = 0; nt < 4; nt++) {
                int bo = ((nt << 4) + fn) * GST + (ks << 5) + fk;
                short8 bf1 = *(const short8*)&B1s[bo];
                short8 bf2 = *(const short8*)&B2s[bo];
                acc1[nt] = __builtin_amdgcn_mfma_f32_16x16x32_bf16(af, bf1, acc1[nt], 0, 0, 0);
                acc2[nt] = __builtin_amdgcn_mfma_f32_16x16x32_bf16(af, bf2, acc2[nt], 0, 0, 0);
            }
        }
    }

    int rowb = mbase + (wv << 4) + ((ln >> 4) << 2);
    #pragma unroll
    for (int nt = 0; nt < 4; nt++) {
        int col = nbase + (nt << 4) + fn;
        float bs1 = bp1[col];
        float bs2 = bp1[HID + col];
        #pragma unroll
        for (int r = 0; r < 4; r++) {
            float u1 = acc1[nt][r] + bs1;
            float u2 = acc2[nt][r] + bs2;
            act[(size_t)(rowb + r) * HID + col] = u1 * (1.0f / (1.0f + expf(-u2)));
        }
    }
}

// ---------------- RoPE + per-head RMSNorm (one wave per (t, head)) ----------------
__global__ __launch_bounds__(64) void rope_rms_kernel(float* __restrict__ x,
                                                      const float* __restrict__ w, int nh)
{
    int t = blockIdx.x, h = blockIdx.y, d = threadIdx.x;
    int base = (t * nh + h) * HD;
    int i = d & 31;
    float x1 = x[base + i];
    float x2 = x[base + 32 + i];
    float inv = 1.0f / powf(10000.0f, (float)(2 * i) * (1.0f / HD));
    float fr = (float)t * inv;
    float c = cosf(fr), s = sinf(fr);
    float r = (d < 32) ? (x1 * c - x2 * s) : (x1 * s + x2 * c);
    float sq = r * r;
    #pragma unroll
    for (int m = 32; m >= 1; m >>= 1) sq += __shfl_xor(sq, m);
    float rs = 1.0f / sqrtf(sq * (1.0f / HD) + EPSF);
    __syncthreads();
    x[base + d] = r * rs * w[d];
}

// ---------------- MFMA flash attention (causal GQA, swapped-QK^T) ----------------
// Per block: head h, 64 q rows. 4 waves; wave w owns q cols [16w,16w+16).
// Swapped QK^T: mfma(A=K, B=Q) -> S^T[kv][q]; lane (c=l&15,g=l>>4) owns q col c,
// kv = 16*mt + 4*g + r. Softmax per-lane scalar + shfl_xor(16,32) over g-groups.
// P^T stays in registers; PV B-frags built via ds_bpermute exchange.
// K in LDS row-major bf16 [kv][d] (A-operand for QK^T); V^T in LDS bf16 [d][kv]
// (A-operand for PV -> O^T). Both double-buffered, reg-prefetch of tile t+1.
// Scale 1/8 folded into Q at bf16 pack (exact). O^T -> O via LDS f32 transpose.
__global__ __launch_bounds__(256) void fattn_kernel(const float* __restrict__ q,
                                                    const float* __restrict__ k,
                                                    const float* __restrict__ v,
                                                    float* __restrict__ o)
{
    __shared__ short lds[2][2][64 * GST];   // [buf][0=K,1=V^T] ; 36864 B

    int h = blockIdx.x, qt = blockIdx.y;
    int kvh = h >> 2;
    int tid = threadIdx.x;
    int w = tid >> 6, ln = tid & 63;
    int c = ln & 15, g = ln >> 4;
    int qbase = qt * 64;
    const size_t krow = (size_t)NKV * HD;   // floats per token row in k/v

    // ---- Q B-fragments (lane: row qbase+16w+c, d = 8g + 32ks + i), scale folded
    short8 qf[2];
    {
        const float* qp = q + ((size_t)(qbase + 16 * w + c) * NQ + h) * HD + 8 * g;
        #pragma unroll
        for (int ks = 0; ks < 2; ks++) {
            float4 a = *(const float4*)(qp + 32 * ks);
            float4 b = *(const float4*)(qp + 32 * ks + 4);
            s8u t;
            t.u[0] = pk2(a.x * 0.125f, a.y * 0.125f);
            t.u[1] = pk2(a.z * 0.125f, a.w * 0.125f);
            t.u[2] = pk2(b.x * 0.125f, b.y * 0.125f);
            t.u[3] = pk2(b.z * 0.125f, b.w * 0.125f);
            qf[ks] = t.s;
        }
    }

    // ---- staging index maps
    int kr[4], kd4[4];                       // K: flat float4 id -> (row, d-quad)
    #pragma unroll
    for (int i = 0; i < 4; i++) { int f4 = tid + 256 * i; kr[i] = f4 >> 4; kd4[i] = f4 & 15; }
    int vd = tid & 63, vrb = (tid >> 6) << 4; // V: lane owns column d=vd, rows vrb..vrb+15

    // ---- prologue: load tile 0 into regs
    float4 kreg[4];
    float vreg[16];
    {
        const float* kb = k + (size_t)kvh * HD;
        #pragma unroll
        for (int i = 0; i < 4; i++)
            kreg[i] = *(const float4*)(kb + (size_t)kr[i] * krow + kd4[i] * 4);
        const float* vb = v + (size_t)kvh * HD + vd;
        #pragma unroll
        for (int i = 0; i < 16; i++)
            vreg[i] = vb[(size_t)(vrb + i) * krow];
    }

    float m_i = -INFINITY, l_i = 0.f;
    floatx4 ot[4];
    #pragma unroll
    for (int mt = 0; mt < 4; mt++)
        #pragma unroll
        for (int r = 0; r < 4; r++) ot[mt][r] = 0.f;

    for (int kt = 0; kt <= qt; kt++) {
        short* KB = lds[kt & 1][0];
        short* VT = lds[kt & 1][1];

        // write staged regs -> LDS (bf16)
        #pragma unroll
        for (int i = 0; i < 4; i++) {
            uint2 wp; wp.x = pk2(kreg[i].x, kreg[i].y); wp.y = pk2(kreg[i].z, kreg[i].w);
            *(uint2*)&KB[kr[i] * GST + kd4[i] * 4] = wp;
        }
        {
            unsigned int u[8];
            #pragma unroll
            for (int i = 0; i < 8; i++) u[i] = pk2(vreg[2 * i], vreg[2 * i + 1]);
            *(uint4*)&VT[vd * GST + vrb]     = make_uint4(u[0], u[1], u[2], u[3]);
            *(uint4*)&VT[vd * GST + vrb + 8] = make_uint4(u[4], u[5], u[6], u[7]);
        }
        __syncthreads();

        // prefetch next tile into regs (overlaps with compute below)
        if (kt < qt) {
            int kb2 = (kt + 1) * 64;
            const float* kb = k + ((size_t)kb2 * NKV + kvh) * HD;
            #pragma unroll
            for (int i = 0; i < 4; i++)
                kreg[i] = *(const float4*)(kb + (size_t)kr[i] * krow + kd4[i] * 4);
            const float* vb = k == v ? nullptr : v; // keep compiler honest
            const float* vp = v + ((size_t)kb2 * NKV + kvh) * HD + vd;
            (void)vb;
            #pragma unroll
            for (int i = 0; i < 16; i++)
                vreg[i] = vp[(size_t)(vrb + i) * krow];
        }

        // ---- QK^T (S^T tile): lane gets p[mt][r] = S^T[16mt+4g+r][c]
        float p[4][4];
        #pragma unroll
        for (int mt = 0; mt < 4; mt++) {
            floatx4 s = {0.f, 0.f, 0.f, 0.f};
            #pragma unroll
            for (int ks = 0; ks < 2; ks++) {
                short8 kf = *(const short8*)&KB[(16 * mt + c) * GST + 32 * ks + 8 * g];
                s = __builtin_amdgcn_mfma_f32_16x16x32_bf16(kf, qf[ks], s, 0, 0, 0);
            }
            #pragma unroll
            for (int r = 0; r < 4; r++) p[mt][r] = s[r];
        }

        if (kt == qt) {   // causal mask on diagonal tile: kv_local > q_local
            #pragma unroll
            for (int mt = 0; mt < 4; mt++)
                #pragma unroll
                for (int r = 0; r < 4; r++)
                    if (16 * mt + 4 * g + r > 16 * w + c) p[mt][r] = -1e30f;
        }

        // ---- online softmax (per-lane scalar; reduce over g-groups)
        float tm = p[0][0];
        #pragma unroll
        for (int mt = 0; mt < 4; mt++)
            #pragma unroll
            for (int r = 0; r < 4; r++) tm = fmaxf(tm, p[mt][r]);
        tm = fmaxf(tm, __shfl_xor(tm, 16));
        tm = fmaxf(tm, __shfl_xor(tm, 32));
        float mn = fmaxf(m_i, tm);
        float alpha = __expf(m_i - mn);
        float ts = 0.f;
        #pragma unroll
        for (int mt = 0; mt < 4; mt++)
            #pragma unroll
            for (int r = 0; r < 4; r++) {
                float e = __expf(p[mt][r] - mn);
                p[mt][r] = e; ts += e;
            }
        ts += __shfl_xor(ts, 16);
        ts += __shfl_xor(ts, 32);
        l_i = alpha * l_i + ts;
        m_i = mn;
        #pragma unroll
        for (int mt = 0; mt < 4; mt++)
            #pragma unroll
            for (int r = 0; r < 4; r++) ot[mt][r] *= alpha;

        // ---- pack P to bf16 pairs (r0r1, r2r3 per mt)
        unsigned int pd[4][2];
        #pragma unroll
        for (int mt = 0; mt < 4; mt++) {
            pd[mt][0] = pk2(p[mt][0], p[mt][1]);
            pd[mt][1] = pk2(p[mt][2], p[mt][3]);
        }

        // ---- build PV B-frags: lane needs P^T[8g+32ks+i][c], i=0..7.
        // kv=8g+32ks+i -> mt_src = 2ks+(g>>1); src lanes gA=2*(g&1) (i<4), gB=gA+1.
        int srcA = c + ((ln & 16) << 1);   // c + 32*(g&1)
        int srcB = srcA + 16;
        int gh = g >> 1;
        short8 pf[2];
        #pragma unroll
        for (int ks = 0; ks < 2; ks++) {
            s8u t;
            unsigned int a0 = (unsigned)__shfl((int)pd[2 * ks][0],     srcA);
            unsigned int a1 = (unsigned)__shfl((int)pd[2 * ks + 1][0], srcA);
            t.u[0] = gh ? a1 : a0;
            unsigned int b0 = (unsigned)__shfl((int)pd[2 * ks][1],     srcA);
            unsigned int b1 = (unsigned)__shfl((int)pd[2 * ks + 1][1], srcA);
            t.u[1] = gh ? b1 : b0;
            unsigned int c0 = (unsigned)__shfl((int)pd[2 * ks][0],     srcB);
            unsigned int c1 = (unsigned)__shfl((int)pd[2 * ks + 1][0], srcB);
            t.u[2] = gh ? c1 : c0;
            unsigned int d0 = (unsigned)__shfl((int)pd[2 * ks][1],     srcB);
            unsigned int d1 = (unsigned)__shfl((int)pd[2 * ks + 1][1], srcB);
            t.u[3] = gh ? d1 : d0;
            pf[ks] = t.s;
        }

        // ---- PV: O^T[d][q] += V^T P^T ; A-frag from VT, d-block mt
        #pragma unroll
        for (int mt = 0; mt < 4; mt++) {
            #pragma unroll
            for (int ks = 0; ks < 2; ks++) {
                short8 vf = *(const short8*)&VT[(16 * mt + c) * GST + 32 * ks + 8 * g];
                ot[mt] = __builtin_amdgcn_mfma_f32_16x16x32_bf16(vf, pf[ks], ot[mt], 0, 0, 0);
            }
        }
    }

    // ---- epilogue: normalize, transpose O^T -> O via LDS, coalesced store
    __syncthreads();
    float* OT = (float*)lds;    // [64][68] f32 = 17408 B (overlays dbuf)
    float rl = 1.0f / l_i;
    #pragma unroll
    for (int mt = 0; mt < 4; mt++)
        #pragma unroll
        for (int r = 0; r < 4; r++)
            OT[(16 * w + c) * 68 + 16 * mt + 4 * g + r] = ot[mt][r] * rl;
    __syncthreads();
    #pragma unroll
    for (int i = 0; i < 4; i++) {
        int idx = tid + 256 * i;
        int rq = idx >> 4, d4 = idx & 15;
        float4 val = *(const float4*)&OT[rq * 68 + d4 * 4];
        *(float4*)(o + ((size_t)(qbase + rq) * NQ + h) * HD + d4 * 4) = val;
    }
}

// ---------------- Per-head sigmoid gate (in-place) ----------------
__global__ __launch_bounds__(64) void gate_kernel(float* __restrict__ o,
                                                  const float* __restrict__ Wg,
                                                  const float* __restrict__ bg)
{
    int t = blockIdx.x, h = blockIdx.y, d = threadIdx.x;
    __shared__ float ao[HD];
    int base = (t * NQ + h) * HD;
    ao[d] = o[base + d];
    __syncthreads();
    float acc = bg[d];
    #pragma unroll 8
    for (int e = 0; e < HD; e++) acc += ao[e] * Wg[e * HD + d];
    float g = 1.0f / (1.0f + expf(-acc));
    o[base + d] = ao[d] * g;
}

// ---------------- Router: logits + argmax (one wave per token) ----------------
__global__ __launch_bounds__(64) void router_kernel(const float* __restrict__ h2,
                                                    const float* __restrict__ Wr,
                                                    const float* __restrict__ br,
                                                    int* __restrict__ top1)
{
    int t = blockIdx.x, lane = threadIdx.x;
    float acc[NE] = {0.f, 0.f, 0.f, 0.f, 0.f, 0.f, 0.f, 0.f};
    for (int d = lane; d < DIM; d += 64) {
        float hv = h2[(size_t)t * DIM + d];
        float4 w0 = *(const float4*)(Wr + (size_t)d * NE);
        float4 w1 = *(const float4*)(Wr + (size_t)d * NE + 4);
        acc[0] += hv * w0.x; acc[1] += hv * w0.y;
        acc[2] += hv * w0.z; acc[3] += hv * w0.w;
        acc[4] += hv * w1.x; acc[5] += hv * w1.y;
        acc[6] += hv * w1.z; acc[7] += hv * w1.w;
    }
    #pragma unroll
    for (int e = 0; e < NE; e++)
        for (int off = 32; off >= 1; off >>= 1) acc[e] += __shfl_down(acc[e], off);
    if (lane == 0) {
        float best = acc[0] + br[0]; int be = 0;
        #pragma unroll
        for (int e = 1; e < NE; e++) {
            float l = acc[e] + br[e];
            if (l > best) { best = l; be = e; }   // strict > : first max wins (np.argmax)
        }
        top1[t] = be;
    }
}

// ---------------- Bucket tokens by expert into 64-padded tiles ----------------
// Single-wave parallel bucketing (lane owns 16 tokens; shfl_up prefix scan).
__global__ __launch_bounds__(64) void bucket_kernel(const int* __restrict__ top1,
                                                    int* __restrict__ perm,
                                                    int* __restrict__ tile_expert)
{
    int lane = threadIdx.x;

    int e_of[16];
    {
        const int4* tp = (const int4*)(top1 + lane * 16);
        #pragma unroll
        for (int c = 0; c < 4; c++) {
            int4 v = tp[c];
            e_of[c * 4 + 0] = v.x & 7;
            e_of[c * 4 + 1] = v.y & 7;
            e_of[c * 4 + 2] = v.z & 7;
            e_of[c * 4 + 3] = v.w & 7;
        }
    }

    int cnt[NE];
    #pragma unroll
    for (int e = 0; e < NE; e++) {
        int c = 0;
        #pragma unroll
        for (int i = 0; i < 16; i++) c += (e_of[i] == e) ? 1 : 0;
        cnt[e] = c;
    }

    int pre[NE];
    #pragma unroll
    for (int e = 0; e < NE; e++) pre[e] = cnt[e];
    #pragma unroll
    for (int off = 1; off < 64; off <<= 1) {
        #pragma unroll
        for (int e = 0; e < NE; e++) {
            int t = __shfl_up(pre[e], off);
            if (lane >= off) pre[e] += t;
        }
    }
    int tot[NE];
    #pragma unroll
    for (int e = 0; e < NE; e++) {
        tot[e] = __shfl(pre[e], 63);
        pre[e] -= cnt[e];
    }

    int off_e[NE + 1];
    off_e[0] = 0;
    #pragma unroll
    for (int e = 0; e < NE; e++)
        off_e[e + 1] = off_e[e] + (((tot[e] + 63) >> 6) << 6);

    if (lane < MAX_TILES) {
        int tb = lane << 6;
        int te = -1;
        #pragma unroll
        for (int e = 0; e < NE; e++)
            if (tb >= off_e[e] && tb < off_e[e + 1]) te = e;
        tile_expert[lane] = te;
    }

    #pragma unroll
    for (int e = 0; e < NE; e++)
        for (int i = off_e[e] + tot[e] + lane; i < off_e[e + 1]; i += 64)
            perm[i] = -1;

    #pragma unroll
    for (int e = 0; e < NE; e++) {
        int pos = off_e[e] + pre[e];
        #pragma unroll
        for (int i = 0; i < 16; i++) {
            if (e_of[i] == e) { perm[pos] = lane * 16 + i; pos++; }
        }
    }
}

extern "C" void kernel_launch(void* const* d_in, const int* in_sizes, int n_in,
                              void* d_out, int out_size, void* d_ws, size_t ws_size,
                              hipStream_t stream)
{
    const float* x    = (const float*)d_in[0];
    const float* ln1w = (const float*)d_in[1];
    const float* ln2w = (const float*)d_in[2];
    const float* Wq   = (const float*)d_in[3];
    const float* bq   = (const float*)d_in[4];
    const float* Wk   = (const float*)d_in[5];
    const float* bk   = (const float*)d_in[6];
    const float* Wv   = (const float*)d_in[7];
    const float* bv   = (const float*)d_in[8];
    const float* qnw  = (const float*)d_in[9];
    const float* knw  = (const float*)d_in[10];
    const float* Wg   = (const float*)d_in[11];
    const float* bg   = (const float*)d_in[12];
    const float* Wo   = (const float*)d_in[13];
    const float* bo   = (const float*)d_in[14];
    const float* Wr   = (const float*)d_in[15];
    const float* br   = (const float*)d_in[16];
    const float* W1   = (const float*)d_in[17];
    const float* b1   = (const float*)d_in[18];
    const float* W2   = (const float*)d_in[19];
    const float* b2   = (const float*)d_in[20];
    float* out = (float*)d_out;
    (void)in_sizes; (void)n_in; (void)out_size; (void)ws_size;

    char* ws = (char*)d_ws;
    float* h    = (float*)(ws);
    float* q    = (float*)(ws + ((size_t)4  << 20));
    float* kbuf = (float*)(ws + ((size_t)8  << 20));
    float* vbuf = (float*)(ws + ((size_t)9  << 20));
    float* ao   = (float*)(ws + ((size_t)10 << 20));
    float* x2   = (float*)(ws);                          // over h (dead)
    float* h2   = (float*)(ws + ((size_t)4  << 20));     // over q (dead)
    float* act  = (float*)(ws + ((size_t)8  << 20));     // over k/v/ao (dead), 12 MB
    int* top1   = (int*)  (ws + ((size_t)20 << 20));
    int* perm   = top1 + 2048;
    int* texp   = perm + MAX_TILES * 64;

    rmsnorm_kernel<<<SEQ, 256, 0, stream>>>(x, ln1w, h);
    gemm_kernel<<<dim3(DIM / 64, SEQ / 64), 256, 0, stream>>>(
        h, Wq, bq, q, nullptr, nullptr, nullptr, DIM, DIM, 0);
    gemm_kernel<<<dim3((NKV * HD) / 64, SEQ / 64), 256, 0, stream>>>(
        h, Wk, bk, kbuf, nullptr, nullptr, nullptr, NKV * HD, DIM, 0);
    gemm_kernel<<<dim3((NKV * HD) / 64, SEQ / 64), 256, 0, stream>>>(
        h, Wv, bv, vbuf, nullptr, nullptr, nullptr, NKV * HD, DIM, 0);
    rope_rms_kernel<<<dim3(SEQ, NQ),  64, 0, stream>>>(q,    qnw, NQ);
    rope_rms_kernel<<<dim3(SEQ, NKV), 64, 0, stream>>>(kbuf, knw, NKV);
    fattn_kernel<<<dim3(NQ, SEQ / 64), 256, 0, stream>>>(q, kbuf, vbuf, ao);
    gate_kernel<<<dim3(SEQ, NQ), 64, 0, stream>>>(ao, Wg, bg);
    gemm_kernel<<<dim3(DIM / 64, SEQ / 64), 256, 0, stream>>>(
        ao, Wo, bo, x2, x, nullptr, nullptr, DIM, DIM, 1);
    rmsnorm_kernel<<<SEQ, 256, 0, stream>>>(x2, ln2w, h2);
    router_kernel<<<SEQ, 64, 0, stream>>>(h2, Wr, br, top1);
    bucket_kernel<<<1, 64, 0, stream>>>(top1, perm, texp);
    moe1_kernel<<<dim3(HID / 64, MAX_TILES), 256, 0, stream>>>(
        h2, W1, b1, act, perm, texp);
    gemm_kernel<<<dim3(DIM / 64, MAX_TILES), 256, 0, stream>>>(
        act, W2, b2, out, x2, perm, texp, DIM, HID, 2);
}

// Round 3
// 436.913 us; speedup vs baseline: 1.5735x; 1.1346x over previous
//
#include <hip/hip_runtime.h>
#include <hip/hip_bf16.h>
#include <cstddef>

#define DIM 1024
#define NQ 16
#define NKV 4
#define HD 64
#define HID 2048
#define NE 8
#define SEQ 1024
#define EPSF 1e-6f
#define MAX_TILES 24   // max sum of ceil(cnt_e/64): 1024/64 + 8 = 24
#define GST 72         // LDS k-stride in bf16 elems: 144 B, 16B-aligned rows

typedef __hip_bfloat16 bf16;
typedef __attribute__((ext_vector_type(8))) short short8;   // 8 bf16 = one MFMA A/B frag
typedef __attribute__((ext_vector_type(4))) float floatx4;  // MFMA C/D frag

typedef union { short8 s; unsigned int u[4]; } s8u;

__device__ __forceinline__ unsigned int f2b(float f) {
    union { bf16 b; unsigned short s; } u;
    u.b = __float2bfloat16(f);
    return (unsigned int)u.s;
}
__device__ __forceinline__ unsigned int pk2(float a, float b) {
    return f2b(a) | (f2b(b) << 16);
}

// ---------------- RMSNorm (row of 1024, f32 in/out) ----------------
__global__ __launch_bounds__(256) void rmsnorm_kernel(const float* __restrict__ src,
                                                      const float* __restrict__ w,
                                                      float* __restrict__ dst)
{
    int row = blockIdx.x, tid = threadIdx.x;
    __shared__ float red[256];
    float vals[4];
    float sq = 0.f;
    size_t base = (size_t)row * DIM;
    #pragma unroll
    for (int i = 0; i < 4; i++) {
        int idx = tid + i * 256;
        float v = src[base + idx];
        vals[i] = v; sq += v * v;
    }
    red[tid] = sq; __syncthreads();
    for (int s = 128; s > 0; s >>= 1) {
        if (tid < s) red[tid] += red[tid + s];
        __syncthreads();
    }
    float rs = 1.0f / sqrtf(red[0] * (1.0f / DIM) + EPSF);
    #pragma unroll
    for (int i = 0; i < 4; i++) {
        int idx = tid + i * 256;
        dst[base + idx] = w[idx] * vals[i] * rs;
    }
}

// ---------------- MFMA bf16 tiled GEMM (64x64 tile, BK=64, 2-phase prefetch) ----
// C[M,N] = A[M,K](f32 -> bf16) @ B[K,N](f32 weights) + bias
// mode 0: C = acc + bias ; mode 1: += resf[row] ; mode 2: perm-scatter + resf[tok]
// Pipeline: prologue-load tile0 -> {write LDS; bar; issue load t+1; MFMA t; bar}.
// Loads have the whole MFMA phase to land (T14/T3-minimum, same as fattn R1 win).
__global__ __launch_bounds__(256) void gemm_kernel(
    const float* __restrict__ A, const float* __restrict__ B, const float* __restrict__ bias,
    float* __restrict__ C, const float* __restrict__ resf,
    const int* __restrict__ perm, const int* __restrict__ tile_expert,
    int N, int K, int mode)
{
    __shared__ short As[64 * GST];
    __shared__ short Bs[64 * GST];
    int tid = threadIdx.x;
    int mbase = blockIdx.y * 64, nbase = blockIdx.x * 64;

    size_t Beoff = 0, biasoff = 0;
    if (tile_expert) {
        int e = tile_expert[blockIdx.y];
        if (e < 0) return;
        Beoff = (size_t)e * K * N;
        biasoff = (size_t)e * N;
    }

    int ar = tid >> 4, ak = (tid & 15) << 2;        // A staging: 4 rows x float4
    int bn = tid & 63, bkk = (tid >> 6) << 4;       // B staging: col bn, 16 k-rows
    const float* BpBase = B + Beoff + (size_t)bkk * N + nbase + bn;

    int wv = tid >> 6, ln = tid & 63;
    int fm = (wv << 4) + (ln & 15);
    int fn = ln & 15;
    int fk = (ln >> 4) << 3;

    floatx4 acc[4];
    #pragma unroll
    for (int nt = 0; nt < 4; nt++)
        #pragma unroll
        for (int r = 0; r < 4; r++) acc[nt][r] = 0.f;

    // prologue: tile 0 -> regs
    float4 apre[4];
    float bpre[16];
    #pragma unroll
    for (int p = 0; p < 4; p++)
        apre[p] = *(const float4*)(A + (size_t)(mbase + (p << 4) + ar) * K + ak);
    #pragma unroll
    for (int i = 0; i < 16; i++)
        bpre[i] = BpBase[(size_t)i * N];

    for (int kt = 0; kt < K; kt += 64) {
        // staged regs -> LDS
        #pragma unroll
        for (int p = 0; p < 4; p++) {
            int m = (p << 4) + ar;
            uint2 wpk; wpk.x = pk2(apre[p].x, apre[p].y); wpk.y = pk2(apre[p].z, apre[p].w);
            *(uint2*)&As[m * GST + ak] = wpk;
        }
        {
            unsigned int u[8];
            #pragma unroll
            for (int i = 0; i < 8; i++) u[i] = pk2(bpre[2 * i], bpre[2 * i + 1]);
            *(uint4*)&Bs[bn * GST + bkk]     = make_uint4(u[0], u[1], u[2], u[3]);
            *(uint4*)&Bs[bn * GST + bkk + 8] = make_uint4(u[4], u[5], u[6], u[7]);
        }
        __syncthreads();

        int kn = kt + 64;
        if (kn < K) {   // issue next tile's loads; they land during MFMA below
            #pragma unroll
            for (int p = 0; p < 4; p++)
                apre[p] = *(const float4*)(A + (size_t)(mbase + (p << 4) + ar) * K + kn + ak);
            const float* bp = BpBase + (size_t)kn * N;
            #pragma unroll
            for (int i = 0; i < 16; i++) bpre[i] = bp[(size_t)i * N];
        }

        #pragma unroll
        for (int ks = 0; ks < 2; ks++) {
            short8 af = *(const short8*)&As[fm * GST + (ks << 5) + fk];
            #pragma unroll
            for (int nt = 0; nt < 4; nt++) {
                short8 bf = *(const short8*)&Bs[((nt << 4) + fn) * GST + (ks << 5) + fk];
                acc[nt] = __builtin_amdgcn_mfma_f32_16x16x32_bf16(af, bf, acc[nt], 0, 0, 0);
            }
        }
        __syncthreads();
    }

    int rowb = mbase + (wv << 4) + ((ln >> 4) << 2);
    if (mode == 2) {
        int tk[4];
        #pragma unroll
        for (int r = 0; r < 4; r++) tk[r] = perm[rowb + r];
        #pragma unroll
        for (int nt = 0; nt < 4; nt++) {
            int col = nbase + (nt << 4) + fn;
            float bsv = bias[biasoff + col];
            #pragma unroll
            for (int r = 0; r < 4; r++)
                if (tk[r] >= 0)
                    C[(size_t)tk[r] * N + col] = resf[(size_t)tk[r] * N + col] + acc[nt][r] + bsv;
        }
    } else {
        #pragma unroll
        for (int nt = 0; nt < 4; nt++) {
            int col = nbase + (nt << 4) + fn;
            float bsv = bias[col];
            #pragma unroll
            for (int r = 0; r < 4; r++) {
                float vv = acc[nt][r] + bsv;
                if (mode == 1) vv += resf[(size_t)(rowb + r) * N + col];
                C[(size_t)(rowb + r) * N + col] = vv;
            }
        }
    }
}

// ---------------- Fused Q/K/V projection (one dispatch, per-block target select) ----
// blockIdx.x: [0,16) -> Wq/bq/q (N=1024); [16,20) -> Wk/bk/k (N=256); [20,24) -> Wv.
// Same 64x64 MFMA tile + 2-phase prefetch as gemm_kernel, mode-0 epilogue.
__global__ __launch_bounds__(256) void qkv_kernel(
    const float* __restrict__ A,
    const float* __restrict__ Wq, const float* __restrict__ bq,
    const float* __restrict__ Wk, const float* __restrict__ bk,
    const float* __restrict__ Wv, const float* __restrict__ bv,
    float* __restrict__ qo, float* __restrict__ ko, float* __restrict__ vo)
{
    __shared__ short As[64 * GST];
    __shared__ short Bs[64 * GST];
    int tid = threadIdx.x;
    int bx = blockIdx.x;
    int mbase = blockIdx.y * 64;

    const float* B; const float* bias; float* C; int N, nbase;
    if (bx < 16)      { B = Wq; bias = bq; C = qo; N = DIM;      nbase = bx * 64; }
    else if (bx < 20) { B = Wk; bias = bk; C = ko; N = NKV * HD; nbase = (bx - 16) * 64; }
    else              { B = Wv; bias = bv; C = vo; N = NKV * HD; nbase = (bx - 20) * 64; }

    int ar = tid >> 4, ak = (tid & 15) << 2;
    int bn = tid & 63, bkk = (tid >> 6) << 4;
    const float* BpBase = B + (size_t)bkk * N + nbase + bn;

    int wv = tid >> 6, ln = tid & 63;
    int fm = (wv << 4) + (ln & 15);
    int fn = ln & 15;
    int fk = (ln >> 4) << 3;

    floatx4 acc[4];
    #pragma unroll
    for (int nt = 0; nt < 4; nt++)
        #pragma unroll
        for (int r = 0; r < 4; r++) acc[nt][r] = 0.f;

    float4 apre[4];
    float bpre[16];
    #pragma unroll
    for (int p = 0; p < 4; p++)
        apre[p] = *(const float4*)(A + (size_t)(mbase + (p << 4) + ar) * DIM + ak);
    #pragma unroll
    for (int i = 0; i < 16; i++)
        bpre[i] = BpBase[(size_t)i * N];

    for (int kt = 0; kt < DIM; kt += 64) {
        #pragma unroll
        for (int p = 0; p < 4; p++) {
            int m = (p << 4) + ar;
            uint2 wpk; wpk.x = pk2(apre[p].x, apre[p].y); wpk.y = pk2(apre[p].z, apre[p].w);
            *(uint2*)&As[m * GST + ak] = wpk;
        }
        {
            unsigned int u[8];
            #pragma unroll
            for (int i = 0; i < 8; i++) u[i] = pk2(bpre[2 * i], bpre[2 * i + 1]);
            *(uint4*)&Bs[bn * GST + bkk]     = make_uint4(u[0], u[1], u[2], u[3]);
            *(uint4*)&Bs[bn * GST + bkk + 8] = make_uint4(u[4], u[5], u[6], u[7]);
        }
        __syncthreads();

        int kn = kt + 64;
        if (kn < DIM) {
            #pragma unroll
            for (int p = 0; p < 4; p++)
                apre[p] = *(const float4*)(A + (size_t)(mbase + (p << 4) + ar) * DIM + kn + ak);
            const float* bp = BpBase + (size_t)kn * N;
            #pragma unroll
            for (int i = 0; i < 16; i++) bpre[i] = bp[(size_t)i * N];
        }

        #pragma unroll
        for (int ks = 0; ks < 2; ks++) {
            short8 af = *(const short8*)&As[fm * GST + (ks << 5) + fk];
            #pragma unroll
            for (int nt = 0; nt < 4; nt++) {
                short8 bf = *(const short8*)&Bs[((nt << 4) + fn) * GST + (ks << 5) + fk];
                acc[nt] = __builtin_amdgcn_mfma_f32_16x16x32_bf16(af, bf, acc[nt], 0, 0, 0);
            }
        }
        __syncthreads();
    }

    int rowb = mbase + (wv << 4) + ((ln >> 4) << 2);
    #pragma unroll
    for (int nt = 0; nt < 4; nt++) {
        int col = nbase + (nt << 4) + fn;
        float bsv = bias[col];
        #pragma unroll
        for (int r = 0; r < 4; r++)
            C[(size_t)(rowb + r) * N + col] = acc[nt][r] + bsv;
    }
}

// ---------------- Fused MoE up-proj + SwiGLU (MFMA bf16, dual-B, prefetch) -------
__global__ __launch_bounds__(256) void moe1_kernel(
    const float* __restrict__ A,        // h2 [SEQ][DIM]
    const float* __restrict__ W1,       // [E][DIM][2*HID]
    const float* __restrict__ b1,       // [E][2*HID]
    float* __restrict__ act,            // [MAX_TILES*64][HID]
    const int* __restrict__ perm,
    const int* __restrict__ tile_expert)
{
    __shared__ short As[64 * GST];
    __shared__ short B1s[64 * GST];
    __shared__ short B2s[64 * GST];
    int tid = threadIdx.x;
    int mbase = blockIdx.y * 64, nbase = blockIdx.x * 64;
    int e = tile_expert[blockIdx.y];
    if (e < 0) return;
    const float* Wp = W1 + (size_t)e * DIM * (2 * HID);
    const float* bp1 = b1 + (size_t)e * (2 * HID);

    int ar = tid >> 4, ak = (tid & 15) << 2;
    int tok[4];
    #pragma unroll
    for (int p = 0; p < 4; p++) tok[p] = perm[mbase + (p << 4) + ar];

    int bn = tid & 63, bkk = (tid >> 6) << 4;
    const float* BpBase = Wp + (size_t)bkk * (2 * HID) + nbase + bn;

    int wv = tid >> 6, ln = tid & 63;
    int fm = (wv << 4) + (ln & 15);
    int fn = ln & 15;
    int fk = (ln >> 4) << 3;

    floatx4 acc1[4], acc2[4];
    #pragma unroll
    for (int nt = 0; nt < 4; nt++)
        #pragma unroll
        for (int r = 0; r < 4; r++) { acc1[nt][r] = 0.f; acc2[nt][r] = 0.f; }

    // prologue: tile 0 -> regs
    float4 apre[4];
    float b1pre[16], b2pre[16];
    #pragma unroll
    for (int p = 0; p < 4; p++)
        apre[p] = (tok[p] >= 0)
            ? *(const float4*)(A + (size_t)tok[p] * DIM + ak)
            : make_float4(0.f, 0.f, 0.f, 0.f);
    #pragma unroll
    for (int i = 0; i < 16; i++) {
        b1pre[i] = BpBase[(size_t)i * (2 * HID)];
        b2pre[i] = BpBase[(size_t)i * (2 * HID) + HID];
    }

    for (int kt = 0; kt < DIM; kt += 64) {
        #pragma unroll
        for (int p = 0; p < 4; p++) {
            int m = (p << 4) + ar;
            uint2 wpk; wpk.x = pk2(apre[p].x, apre[p].y); wpk.y = pk2(apre[p].z, apre[p].w);
            *(uint2*)&As[m * GST + ak] = wpk;
        }
        {
            unsigned int u1[8], u2[8];
            #pragma unroll
            for (int i = 0; i < 8; i++) {
                u1[i] = pk2(b1pre[2 * i], b1pre[2 * i + 1]);
                u2[i] = pk2(b2pre[2 * i], b2pre[2 * i + 1]);
            }
            *(uint4*)&B1s[bn * GST + bkk]     = make_uint4(u1[0], u1[1], u1[2], u1[3]);
            *(uint4*)&B1s[bn * GST + bkk + 8] = make_uint4(u1[4], u1[5], u1[6], u1[7]);
            *(uint4*)&B2s[bn * GST + bkk]     = make_uint4(u2[0], u2[1], u2[2], u2[3]);
            *(uint4*)&B2s[bn * GST + bkk + 8] = make_uint4(u2[4], u2[5], u2[6], u2[7]);
        }
        __syncthreads();

        int kn = kt + 64;
        if (kn < DIM) {   // issue next tile's loads; land during dual-MFMA below
            #pragma unroll
            for (int p = 0; p < 4; p++)
                apre[p] = (tok[p] >= 0)
                    ? *(const float4*)(A + (size_t)tok[p] * DIM + kn + ak)
                    : make_float4(0.f, 0.f, 0.f, 0.f);
            const float* bp = BpBase + (size_t)kn * (2 * HID);
            #pragma unroll
            for (int i = 0; i < 16; i++) {
                b1pre[i] = bp[(size_t)i * (2 * HID)];
                b2pre[i] = bp[(size_t)i * (2 * HID) + HID];
            }
        }

        #pragma unroll
        for (int ks = 0; ks < 2; ks++) {
            short8 af = *(const short8*)&As[fm * GST + (ks << 5) + fk];
            #pragma unroll
            for (int nt = 0; nt < 4; nt++) {
                int bo = ((nt << 4) + fn) * GST + (ks << 5) + fk;
                short8 bf1 = *(const short8*)&B1s[bo];
                short8 bf2 = *(const short8*)&B2s[bo];
                acc1[nt] = __builtin_amdgcn_mfma_f32_16x16x32_bf16(af, bf1, acc1[nt], 0, 0, 0);
                acc2[nt] = __builtin_amdgcn_mfma_f32_16x16x32_bf16(af, bf2, acc2[nt], 0, 0, 0);
            }
        }
        __syncthreads();
    }

    int rowb = mbase + (wv << 4) + ((ln >> 4) << 2);
    #pragma unroll
    for (int nt = 0; nt < 4; nt++) {
        int col = nbase + (nt << 4) + fn;
        float bs1 = bp1[col];
        float bs2 = bp1[HID + col];
        #pragma unroll
        for (int r = 0; r < 4; r++) {
            float u1 = acc1[nt][r] + bs1;
            float u2 = acc2[nt][r] + bs2;
            act[(size_t)(rowb + r) * HID + col] = u1 * (1.0f / (1.0f + expf(-u2)));
        }
    }
}

// ---------------- RoPE + per-head RMSNorm (one wave per (t, head)) ----------------
__global__ __launch_bounds__(64) void rope_rms_kernel(float* __restrict__ x,
                                                      const float* __restrict__ w, int nh)
{
    int t = blockIdx.x, h = blockIdx.y, d = threadIdx.x;
    int base = (t * nh + h) * HD;
    int i = d & 31;
    float x1 = x[base + i];
    float x2 = x[base + 32 + i];
    float inv = 1.0f / powf(10000.0f, (float)(2 * i) * (1.0f / HD));
    float fr = (float)t * inv;
    float c = cosf(fr), s = sinf(fr);
    float r = (d < 32) ? (x1 * c - x2 * s) : (x1 * s + x2 * c);
    float sq = r * r;
    #pragma unroll
    for (int m = 32; m >= 1; m >>= 1) sq += __shfl_xor(sq, m);
    float rs = 1.0f / sqrtf(sq * (1.0f / HD) + EPSF);
    __syncthreads();
    x[base + d] = r * rs * w[d];
}

// ---------------- MFMA flash attention (causal GQA, swapped-QK^T) ----------------
__global__ __launch_bounds__(256) void fattn_kernel(const float* __restrict__ q,
                                                    const float* __restrict__ k,
                                                    const float* __restrict__ v,
                                                    float* __restrict__ o)
{
    __shared__ short lds[2][2][64 * GST];   // [buf][0=K,1=V^T] ; 36864 B

    int h = blockIdx.x, qt = blockIdx.y;
    int kvh = h >> 2;
    int tid = threadIdx.x;
    int w = tid >> 6, ln = tid & 63;
    int c = ln & 15, g = ln >> 4;
    int qbase = qt * 64;
    const size_t krow = (size_t)NKV * HD;   // floats per token row in k/v

    short8 qf[2];
    {
        const float* qp = q + ((size_t)(qbase + 16 * w + c) * NQ + h) * HD + 8 * g;
        #pragma unroll
        for (int ks = 0; ks < 2; ks++) {
            float4 a = *(const float4*)(qp + 32 * ks);
            float4 b = *(const float4*)(qp + 32 * ks + 4);
            s8u t;
            t.u[0] = pk2(a.x * 0.125f, a.y * 0.125f);
            t.u[1] = pk2(a.z * 0.125f, a.w * 0.125f);
            t.u[2] = pk2(b.x * 0.125f, b.y * 0.125f);
            t.u[3] = pk2(b.z * 0.125f, b.w * 0.125f);
            qf[ks] = t.s;
        }
    }

    int kr[4], kd4[4];
    #pragma unroll
    for (int i = 0; i < 4; i++) { int f4 = tid + 256 * i; kr[i] = f4 >> 4; kd4[i] = f4 & 15; }
    int vd = tid & 63, vrb = (tid >> 6) << 4;

    float4 kreg[4];
    float vreg[16];
    {
        const float* kb = k + (size_t)kvh * HD;
        #pragma unroll
        for (int i = 0; i < 4; i++)
            kreg[i] = *(const float4*)(kb + (size_t)kr[i] * krow + kd4[i] * 4);
        const float* vb = v + (size_t)kvh * HD + vd;
        #pragma unroll
        for (int i = 0; i < 16; i++)
            vreg[i] = vb[(size_t)(vrb + i) * krow];
    }

    float m_i = -INFINITY, l_i = 0.f;
    floatx4 ot[4];
    #pragma unroll
    for (int mt = 0; mt < 4; mt++)
        #pragma unroll
        for (int r = 0; r < 4; r++) ot[mt][r] = 0.f;

    for (int kt = 0; kt <= qt; kt++) {
        short* KB = lds[kt & 1][0];
        short* VT = lds[kt & 1][1];

        #pragma unroll
        for (int i = 0; i < 4; i++) {
            uint2 wp; wp.x = pk2(kreg[i].x, kreg[i].y); wp.y = pk2(kreg[i].z, kreg[i].w);
            *(uint2*)&KB[kr[i] * GST + kd4[i] * 4] = wp;
        }
        {
            unsigned int u[8];
            #pragma unroll
            for (int i = 0; i < 8; i++) u[i] = pk2(vreg[2 * i], vreg[2 * i + 1]);
            *(uint4*)&VT[vd * GST + vrb]     = make_uint4(u[0], u[1], u[2], u[3]);
            *(uint4*)&VT[vd * GST + vrb + 8] = make_uint4(u[4], u[5], u[6], u[7]);
        }
        __syncthreads();

        if (kt < qt) {
            int kb2 = (kt + 1) * 64;
            const float* kb = k + ((size_t)kb2 * NKV + kvh) * HD;
            #pragma unroll
            for (int i = 0; i < 4; i++)
                kreg[i] = *(const float4*)(kb + (size_t)kr[i] * krow + kd4[i] * 4);
            const float* vp = v + ((size_t)kb2 * NKV + kvh) * HD + vd;
            #pragma unroll
            for (int i = 0; i < 16; i++)
                vreg[i] = vp[(size_t)(vrb + i) * krow];
        }

        float p[4][4];
        #pragma unroll
        for (int mt = 0; mt < 4; mt++) {
            floatx4 s = {0.f, 0.f, 0.f, 0.f};
            #pragma unroll
            for (int ks = 0; ks < 2; ks++) {
                short8 kf = *(const short8*)&KB[(16 * mt + c) * GST + 32 * ks + 8 * g];
                s = __builtin_amdgcn_mfma_f32_16x16x32_bf16(kf, qf[ks], s, 0, 0, 0);
            }
            #pragma unroll
            for (int r = 0; r < 4; r++) p[mt][r] = s[r];
        }

        if (kt == qt) {
            #pragma unroll
            for (int mt = 0; mt < 4; mt++)
                #pragma unroll
                for (int r = 0; r < 4; r++)
                    if (16 * mt + 4 * g + r > 16 * w + c) p[mt][r] = -1e30f;
        }

        float tm = p[0][0];
        #pragma unroll
        for (int mt = 0; mt < 4; mt++)
            #pragma unroll
            for (int r = 0; r < 4; r++) tm = fmaxf(tm, p[mt][r]);
        tm = fmaxf(tm, __shfl_xor(tm, 16));
        tm = fmaxf(tm, __shfl_xor(tm, 32));
        float mn = fmaxf(m_i, tm);
        float alpha = __expf(m_i - mn);
        float ts = 0.f;
        #pragma unroll
        for (int mt = 0; mt < 4; mt++)
            #pragma unroll
            for (int r = 0; r < 4; r++) {
                float e = __expf(p[mt][r] - mn);
                p[mt][r] = e; ts += e;
            }
        ts += __shfl_xor(ts, 16);
        ts += __shfl_xor(ts, 32);
        l_i = alpha * l_i + ts;
        m_i = mn;
        #pragma unroll
        for (int mt = 0; mt < 4; mt++)
            #pragma unroll
            for (int r = 0; r < 4; r++) ot[mt][r] *= alpha;

        unsigned int pd[4][2];
        #pragma unroll
        for (int mt = 0; mt < 4; mt++) {
            pd[mt][0] = pk2(p[mt][0], p[mt][1]);
            pd[mt][1] = pk2(p[mt][2], p[mt][3]);
        }

        int srcA = c + ((ln & 16) << 1);
        int srcB = srcA + 16;
        int gh = g >> 1;
        short8 pf[2];
        #pragma unroll
        for (int ks = 0; ks < 2; ks++) {
            s8u t;
            unsigned int a0 = (unsigned)__shfl((int)pd[2 * ks][0],     srcA);
            unsigned int a1 = (unsigned)__shfl((int)pd[2 * ks + 1][0], srcA);
            t.u[0] = gh ? a1 : a0;
            unsigned int b0 = (unsigned)__shfl((int)pd[2 * ks][1],     srcA);
            unsigned int b1 = (unsigned)__shfl((int)pd[2 * ks + 1][1], srcA);
            t.u[1] = gh ? b1 : b0;
            unsigned int c0 = (unsigned)__shfl((int)pd[2 * ks][0],     srcB);
            unsigned int c1 = (unsigned)__shfl((int)pd[2 * ks + 1][0], srcB);
            t.u[2] = gh ? c1 : c0;
            unsigned int d0 = (unsigned)__shfl((int)pd[2 * ks][1],     srcB);
            unsigned int d1 = (unsigned)__shfl((int)pd[2 * ks + 1][1], srcB);
            t.u[3] = gh ? d1 : d0;
            pf[ks] = t.s;
        }

        #pragma unroll
        for (int mt = 0; mt < 4; mt++) {
            #pragma unroll
            for (int ks = 0; ks < 2; ks++) {
                short8 vf = *(const short8*)&VT[(16 * mt + c) * GST + 32 * ks + 8 * g];
                ot[mt] = __builtin_amdgcn_mfma_f32_16x16x32_bf16(vf, pf[ks], ot[mt], 0, 0, 0);
            }
        }
    }

    __syncthreads();
    float* OT = (float*)lds;    // [64][68] f32 (overlays dbuf)
    float rl = 1.0f / l_i;
    #pragma unroll
    for (int mt = 0; mt < 4; mt++)
        #pragma unroll
        for (int r = 0; r < 4; r++)
            OT[(16 * w + c) * 68 + 16 * mt + 4 * g + r] = ot[mt][r] * rl;
    __syncthreads();
    #pragma unroll
    for (int i = 0; i < 4; i++) {
        int idx = tid + 256 * i;
        int rq = idx >> 4, d4 = idx & 15;
        float4 val = *(const float4*)&OT[rq * 68 + d4 * 4];
        *(float4*)(o + ((size_t)(qbase + rq) * NQ + h) * HD + d4 * 4) = val;
    }
}

// ---------------- Per-head sigmoid gate (in-place) ----------------
__global__ __launch_bounds__(64) void gate_kernel(float* __restrict__ o,
                                                  const float* __restrict__ Wg,
                                                  const float* __restrict__ bg)
{
    int t = blockIdx.x, h = blockIdx.y, d = threadIdx.x;
    __shared__ float ao[HD];
    int base = (t * NQ + h) * HD;
    ao[d] = o[base + d];
    __syncthreads();
    float acc = bg[d];
    #pragma unroll 8
    for (int e = 0; e < HD; e++) acc += ao[e] * Wg[e * HD + d];
    float g = 1.0f / (1.0f + expf(-acc));
    o[base + d] = ao[d] * g;
}

// ---------------- Router: logits + argmax (one wave per token) ----------------
__global__ __launch_bounds__(64) void router_kernel(const float* __restrict__ h2,
                                                    const float* __restrict__ Wr,
                                                    const float* __restrict__ br,
                                                    int* __restrict__ top1)
{
    int t = blockIdx.x, lane = threadIdx.x;
    float acc[NE] = {0.f, 0.f, 0.f, 0.f, 0.f, 0.f, 0.f, 0.f};
    for (int d = lane; d < DIM; d += 64) {
        float hv = h2[(size_t)t * DIM + d];
        float4 w0 = *(const float4*)(Wr + (size_t)d * NE);
        float4 w1 = *(const float4*)(Wr + (size_t)d * NE + 4);
        acc[0] += hv * w0.x; acc[1] += hv * w0.y;
        acc[2] += hv * w0.z; acc[3] += hv * w0.w;
        acc[4] += hv * w1.x; acc[5] += hv * w1.y;
        acc[6] += hv * w1.z; acc[7] += hv * w1.w;
    }
    #pragma unroll
    for (int e = 0; e < NE; e++)
        for (int off = 32; off >= 1; off >>= 1) acc[e] += __shfl_down(acc[e], off);
    if (lane == 0) {
        float best = acc[0] + br[0]; int be = 0;
        #pragma unroll
        for (int e = 1; e < NE; e++) {
            float l = acc[e] + br[e];
            if (l > best) { best = l; be = e; }   // strict > : first max wins (np.argmax)
        }
        top1[t] = be;
    }
}

// ---------------- Bucket tokens by expert into 64-padded tiles ----------------
__global__ __launch_bounds__(64) void bucket_kernel(const int* __restrict__ top1,
                                                    int* __restrict__ perm,
                                                    int* __restrict__ tile_expert)
{
    int lane = threadIdx.x;

    int e_of[16];
    {
        const int4* tp = (const int4*)(top1 + lane * 16);
        #pragma unroll
        for (int c = 0; c < 4; c++) {
            int4 v = tp[c];
            e_of[c * 4 + 0] = v.x & 7;
            e_of[c * 4 + 1] = v.y & 7;
            e_of[c * 4 + 2] = v.z & 7;
            e_of[c * 4 + 3] = v.w & 7;
        }
    }

    int cnt[NE];
    #pragma unroll
    for (int e = 0; e < NE; e++) {
        int c = 0;
        #pragma unroll
        for (int i = 0; i < 16; i++) c += (e_of[i] == e) ? 1 : 0;
        cnt[e] = c;
    }

    int pre[NE];
    #pragma unroll
    for (int e = 0; e < NE; e++) pre[e] = cnt[e];
    #pragma unroll
    for (int off = 1; off < 64; off <<= 1) {
        #pragma unroll
        for (int e = 0; e < NE; e++) {
            int t = __shfl_up(pre[e], off);
            if (lane >= off) pre[e] += t;
        }
    }
    int tot[NE];
    #pragma unroll
    for (int e = 0; e < NE; e++) {
        tot[e] = __shfl(pre[e], 63);
        pre[e] -= cnt[e];
    }

    int off_e[NE + 1];
    off_e[0] = 0;
    #pragma unroll
    for (int e = 0; e < NE; e++)
        off_e[e + 1] = off_e[e] + (((tot[e] + 63) >> 6) << 6);

    if (lane < MAX_TILES) {
        int tb = lane << 6;
        int te = -1;
        #pragma unroll
        for (int e = 0; e < NE; e++)
            if (tb >= off_e[e] && tb < off_e[e + 1]) te = e;
        tile_expert[lane] = te;
    }

    #pragma unroll
    for (int e = 0; e < NE; e++)
        for (int i = off_e[e] + tot[e] + lane; i < off_e[e + 1]; i += 64)
            perm[i] = -1;

    #pragma unroll
    for (int e = 0; e < NE; e++) {
        int pos = off_e[e] + pre[e];
        #pragma unroll
        for (int i = 0; i < 16; i++) {
            if (e_of[i] == e) { perm[pos] = lane * 16 + i; pos++; }
        }
    }
}

extern "C" void kernel_launch(void* const* d_in, const int* in_sizes, int n_in,
                              void* d_out, int out_size, void* d_ws, size_t ws_size,
                              hipStream_t stream)
{
    const float* x    = (const float*)d_in[0];
    const float* ln1w = (const float*)d_in[1];
    const float* ln2w = (const float*)d_in[2];
    const float* Wq   = (const float*)d_in[3];
    const float* bq   = (const float*)d_in[4];
    const float* Wk   = (const float*)d_in[5];
    const float* bk   = (const float*)d_in[6];
    const float* Wv   = (const float*)d_in[7];
    const float* bv   = (const float*)d_in[8];
    const float* qnw  = (const float*)d_in[9];
    const float* knw  = (const float*)d_in[10];
    const float* Wg   = (const float*)d_in[11];
    const float* bg   = (const float*)d_in[12];
    const float* Wo   = (const float*)d_in[13];
    const float* bo   = (const float*)d_in[14];
    const float* Wr   = (const float*)d_in[15];
    const float* br   = (const float*)d_in[16];
    const float* W1   = (const float*)d_in[17];
    const float* b1   = (const float*)d_in[18];
    const float* W2   = (const float*)d_in[19];
    const float* b2   = (const float*)d_in[20];
    float* out = (float*)d_out;
    (void)in_sizes; (void)n_in; (void)out_size; (void)ws_size;

    char* ws = (char*)d_ws;
    float* h    = (float*)(ws);
    float* q    = (float*)(ws + ((size_t)4  << 20));
    float* kbuf = (float*)(ws + ((size_t)8  << 20));
    float* vbuf = (float*)(ws + ((size_t)9  << 20));
    float* ao   = (float*)(ws + ((size_t)10 << 20));
    float* x2   = (float*)(ws);                          // over h (dead)
    float* h2   = (float*)(ws + ((size_t)4  << 20));     // over q (dead)
    float* act  = (float*)(ws + ((size_t)8  << 20));     // over k/v/ao (dead), 12 MB
    int* top1   = (int*)  (ws + ((size_t)20 << 20));
    int* perm   = top1 + 2048;
    int* texp   = perm + MAX_TILES * 64;

    rmsnorm_kernel<<<SEQ, 256, 0, stream>>>(x, ln1w, h);
    qkv_kernel<<<dim3(24, SEQ / 64), 256, 0, stream>>>(
        h, Wq, bq, Wk, bk, Wv, bv, q, kbuf, vbuf);
    rope_rms_kernel<<<dim3(SEQ, NQ),  64, 0, stream>>>(q,    qnw, NQ);
    rope_rms_kernel<<<dim3(SEQ, NKV), 64, 0, stream>>>(kbuf, knw, NKV);
    fattn_kernel<<<dim3(NQ, SEQ / 64), 256, 0, stream>>>(q, kbuf, vbuf, ao);
    gate_kernel<<<dim3(SEQ, NQ), 64, 0, stream>>>(ao, Wg, bg);
    gemm_kernel<<<dim3(DIM / 64, SEQ / 64), 256, 0, stream>>>(
        ao, Wo, bo, x2, x, nullptr, nullptr, DIM, DIM, 1);
    rmsnorm_kernel<<<SEQ, 256, 0, stream>>>(x2, ln2w, h2);
    router_kernel<<<SEQ, 64, 0, stream>>>(h2, Wr, br, top1);
    bucket_kernel<<<1, 64, 0, stream>>>(top1, perm, texp);
    moe1_kernel<<<dim3(HID / 64, MAX_TILES), 256, 0, stream>>>(
        h2, W1, b1, act, perm, texp);
    gemm_kernel<<<dim3(DIM / 64, MAX_TILES), 256, 0, stream>>>(
        act, W2, b2, out, x2, perm, texp, DIM, HID, 2);
}